// Round 1
// baseline (58.602 us; speedup 1.0000x reference)
//
#include <hip/hip_runtime.h>
#include <math.h>

// QuantumDecoder: the reference's 2^14-dim state-vector simulation collapses
// analytically:
//   - RX layer  -> product state, P(bit_w=1) = sin^2(latent_w/2), bits independent
//   - CNOT chain -> basis permutation: bit_i -> XOR(b_0..b_i)
//   - RZ layer  -> pure phase, cancels in |amp|^2  => `weights` input is UNUSED
//   => <Z_i> = prod_{w<=i} cos(latent[b,w])   (prefix product of cosines)
// Then out = z @ W_map^T + b_map.  Total ~2.2 MFLOP: launch-latency bound.

constexpr int LATENT = 14;
constexpr int OUT    = 784;
constexpr int BATCH  = 128;

__global__ __launch_bounds__(256)
void qdec_kernel(const float* __restrict__ latent,   // [BATCH, LATENT]
                 const float* __restrict__ W_map,    // [OUT, LATENT]
                 const float* __restrict__ b_map,    // [OUT]
                 float* __restrict__ out)            // [BATCH, OUT]
{
    __shared__ float z[LATENT];

    const int b = blockIdx.y;

    // Stage cosines into LDS (first 14 lanes), then one lane does the
    // 14-element prefix product in place. Trivial serial work.
    if (threadIdx.x < LATENT) {
        z[threadIdx.x] = cosf(latent[b * LATENT + threadIdx.x]);
    }
    __syncthreads();
    if (threadIdx.x == 0) {
        float p = 1.0f;
        #pragma unroll
        for (int i = 0; i < LATENT; ++i) { p *= z[i]; z[i] = p; }
    }
    __syncthreads();

    const int o = blockIdx.x * blockDim.x + threadIdx.x;
    if (o < OUT) {
        float acc = b_map[o];
        const float* wrow = W_map + o * LATENT;   // 56 B row; L1/L2 resident (44 KB total)
        #pragma unroll
        for (int i = 0; i < LATENT; ++i) {
            acc = fmaf(z[i], wrow[i], acc);
        }
        out[b * OUT + o] = acc;
    }
}

extern "C" void kernel_launch(void* const* d_in, const int* in_sizes, int n_in,
                              void* d_out, int out_size, void* d_ws, size_t ws_size,
                              hipStream_t stream)
{
    const float* latent = (const float*)d_in[0];   // [128, 14]
    // d_in[1] = weights [14,14] — provably unused (RZ phases cancel in |.|^2)
    const float* W_map  = (const float*)d_in[2];   // [784, 14]
    const float* b_map  = (const float*)d_in[3];   // [784]
    float*       out    = (float*)d_out;           // [128, 784] fp32

    dim3 grid((OUT + 255) / 256, BATCH);
    qdec_kernel<<<grid, 256, 0, stream>>>(latent, W_map, b_map, out);
}